// Round 3
// baseline (215.190 us; speedup 1.0000x reference)
//
#include <hip/hip_runtime.h>

// Problem: B=4, N=1024, H=64.
// d_out: [0..262143] updated (b,i,d) fp32 ; [262144..4456447] attn (b,i,j) fp32
#define ATTN_OFF 262144

// ws float-slot offsets (1 slot = 4B):
#define WS_HIP  0          // hiP  __half2-packed [b][32 hp][1024 i]   131072 slots
#define WS_HJP  131072     // hjP  same                                 131072
#define WS_L16  262144     // logits fp16 [b][1024][1024]              2097152
#define WS_SMAX 2359296    // smax [16 chunk][4096 row] fp32             65536
#define WS_SSUM 2424832    // ssum [16][4096] fp32                       65536

typedef float4 f4;
typedef _Float16 h2v __attribute__((ext_vector_type(2)));

union F4H { f4 f; h2v h[4]; };
union F2H { float2 f; h2v h[2]; };

__device__ __forceinline__ f4 ld4(const float* p) { return *reinterpret_cast<const f4*>(p); }
__device__ __forceinline__ void st4(float* p, f4 v) { *reinterpret_cast<f4*>(p) = v; }
__device__ __forceinline__ float fdot2f(h2v a, h2v b, float c) {
    return __builtin_amdgcn_fdot2(a, b, c, false);   // v_dot2_f32_f16
}
__device__ __forceinline__ h2v pack2(float a, float b) {
    h2v r; r.x = (_Float16)a; r.y = (_Float16)b; return r;
}

// ---------------- Kernel A: hi' = x@W1a^T + b1 ; hj = x@W1b^T.
// Output packed fp16, h-pair major: hiP[(b*32+hp)*1024 + i] = (hi[i,2hp], hi[i,2hp+1]).
// Also zeroes d_out[0:262144] for kd's atomic accumulation.
__global__ __launch_bounds__(256, 4)
void ka_proj(const float* __restrict__ x, const float* __restrict__ W1,
             const float* __restrict__ b1,
             h2v* __restrict__ hiP, h2v* __restrict__ hjP, float* __restrict__ outz) {
    __shared__ float xT[64 * 68];   // xT[d][i]
    __shared__ float w1T[64 * 68];  // w1T[d][c] = W1[c][z*64+d]
    const int t  = threadIdx.x;
    const int i0 = blockIdx.x * 64;
    const int b  = blockIdx.y;
    const int z  = blockIdx.z;
    // zero the 'updated' region: 128 blocks x 256 thr x 2 f4 = 65536 f4
    {
        const int bid = blockIdx.x + blockIdx.y * 16 + blockIdx.z * 64;
        const int zi  = (bid * 256 + t) * 2;
        f4 zv = make_float4(0.f, 0.f, 0.f, 0.f);
        st4(&outz[(size_t)zi * 4], zv);
        st4(&outz[(size_t)(zi + 1) * 4], zv);
    }
    const int lo = t & 15;
    const int dq = t >> 4;
#pragma unroll
    for (int p = 0; p < 4; ++p) {
        const int il = p * 16 + lo;
        f4 v = ld4(&x[(size_t)(b * 1024 + i0 + il) * 64 + dq * 4]);
        xT[(dq * 4 + 0) * 68 + il] = v.x;
        xT[(dq * 4 + 1) * 68 + il] = v.y;
        xT[(dq * 4 + 2) * 68 + il] = v.z;
        xT[(dq * 4 + 3) * 68 + il] = v.w;
        f4 w = ld4(&W1[(size_t)il * 128 + z * 64 + dq * 4]);
        w1T[(dq * 4 + 0) * 68 + il] = w.x;
        w1T[(dq * 4 + 1) * 68 + il] = w.y;
        w1T[(dq * 4 + 2) * 68 + il] = w.z;
        w1T[(dq * 4 + 3) * 68 + il] = w.w;
    }
    __syncthreads();
    const int tx = t & 15;   // channel quad c = tx*4..tx*4+3
    const int ty = t >> 4;   // i quad
    float acc[4][4];
    if (z == 0) {
        f4 bv = ld4(&b1[tx * 4]);
        float ba[4] = {bv.x, bv.y, bv.z, bv.w};
#pragma unroll
        for (int ii = 0; ii < 4; ++ii)
#pragma unroll
            for (int cc = 0; cc < 4; ++cc) acc[ii][cc] = ba[cc];
    } else {
#pragma unroll
        for (int ii = 0; ii < 4; ++ii)
#pragma unroll
            for (int cc = 0; cc < 4; ++cc) acc[ii][cc] = 0.f;
    }
#pragma unroll 8
    for (int d = 0; d < 64; ++d) {
        f4 xv = ld4(&xT[d * 68 + ty * 4]);
        f4 wv = ld4(&w1T[d * 68 + tx * 4]);
        float xa[4] = {xv.x, xv.y, xv.z, xv.w};
        float wa[4] = {wv.x, wv.y, wv.z, wv.w};
#pragma unroll
        for (int ii = 0; ii < 4; ++ii)
#pragma unroll
            for (int cc = 0; cc < 4; ++cc)
                acc[ii][cc] = fmaf(xa[ii], wa[cc], acc[ii][cc]);
    }
    h2v* outp = z ? hjP : hiP;
#pragma unroll
    for (int p = 0; p < 2; ++p) {    // hp = tx*2+p, pack channels (2hp, 2hp+1)
        F4H u;
#pragma unroll
        for (int ii = 0; ii < 4; ++ii)
            u.h[ii] = pack2(acc[ii][p * 2 + 0], acc[ii][p * 2 + 1]);
        st4((float*)&outp[(size_t)(b * 32 + tx * 2 + p) * 1024 + i0 + ty * 4], u.f);
    }
}

// ---------------- Kernel B: logits (fp16) + per-chunk softmax stats.
// grid (16 jT, 8 iT, 4 b) = 512 blocks, block 256. Tile 128i x 64j, 8x4/thread.
// Inner: pk_add_f16 + pk_max_f16 + v_dot2_f32_f16 => 1.5 instr per (i,j,h).
__global__ __launch_bounds__(256, 4)
void kb_logits(const h2v* __restrict__ hiP, const h2v* __restrict__ hjP,
               const float* __restrict__ W2, _Float16* __restrict__ l16,
               float* __restrict__ smax, float* __restrict__ ssum) {
    __shared__ __align__(16) h2v s_hi[32 * 128];  // [hp][i]
    __shared__ __align__(16) h2v s_hj[32 * 64];   // [hp][j]
    __shared__ h2v s_w2[32];
    const int t  = threadIdx.x;
    const int jT = blockIdx.x;
    const int iT = blockIdx.y;
    const int b  = blockIdx.z;
#pragma unroll
    for (int p = 0; p < 4; ++p) {    // 1024 f4 copies
        const int idx = p * 256 + t;
        const int hp  = idx >> 5;
        const int c4  = (idx & 31) * 4;
        st4((float*)&s_hi[hp * 128 + c4],
            ld4((const float*)&hiP[(size_t)(b * 32 + hp) * 1024 + iT * 128 + c4]));
    }
#pragma unroll
    for (int p = 0; p < 2; ++p) {    // 512 f4 copies
        const int idx = p * 256 + t;
        const int hp  = idx >> 4;
        const int c4  = (idx & 15) * 4;
        st4((float*)&s_hj[hp * 64 + c4],
            ld4((const float*)&hjP[(size_t)(b * 32 + hp) * 1024 + jT * 64 + c4]));
    }
    if (t < 16) {
        f4 w = ld4(&W2[t * 4]);
        s_w2[t * 2]     = pack2(w.x, w.y);
        s_w2[t * 2 + 1] = pack2(w.z, w.w);
    }
    __syncthreads();
    const int tx = t & 15;  // j quad
    const int ty = t >> 4;  // i oct
    float acc[8][4];
#pragma unroll
    for (int ii = 0; ii < 8; ++ii)
#pragma unroll
        for (int jj = 0; jj < 4; ++jj) acc[ii][jj] = 0.f;
    const h2v z2 = (h2v)0;
#pragma unroll 4
    for (int hp = 0; hp < 32; ++hp) {
        F4H a0, a1, bb;
        a0.f = ld4((const float*)&s_hi[hp * 128 + ty * 8]);      // broadcast
        a1.f = ld4((const float*)&s_hi[hp * 128 + ty * 8 + 4]);
        bb.f = ld4((const float*)&s_hj[hp * 64 + tx * 4]);       // 2-way (free)
        const h2v w2p = s_w2[hp];
#pragma unroll
        for (int ii = 0; ii < 8; ++ii) {
            const h2v av = (ii < 4) ? a0.h[ii] : a1.h[ii - 4];
#pragma unroll
            for (int jj = 0; jj < 4; ++jj) {
                h2v r = __builtin_elementwise_max(av + bb.h[jj], z2);
                acc[ii][jj] = fdot2f(r, w2p, acc[ii][jj]);
            }
        }
    }
    // epilogue: fp16 logit store + 16-lane chunk stats
#pragma unroll
    for (int ii = 0; ii < 8; ++ii) {
        const int row = b * 1024 + iT * 128 + ty * 8 + ii;
        F2H uo;
        uo.h[0] = pack2(acc[ii][0], acc[ii][1]);
        uo.h[1] = pack2(acc[ii][2], acc[ii][3]);
        *reinterpret_cast<float2*>(&l16[(size_t)row * 1024 + jT * 64 + tx * 4]) = uo.f;
        float m = fmaxf(fmaxf(acc[ii][0], acc[ii][1]), fmaxf(acc[ii][2], acc[ii][3]));
#pragma unroll
        for (int d = 1; d < 16; d <<= 1) m = fmaxf(m, __shfl_xor(m, d));
        float s = __expf(acc[ii][0] - m) + __expf(acc[ii][1] - m) +
                  __expf(acc[ii][2] - m) + __expf(acc[ii][3] - m);
#pragma unroll
        for (int d = 1; d < 16; d <<= 1) s += __shfl_xor(s, d);
        if (tx == 0) {
            smax[jT * 4096 + row] = m;
            ssum[jT * 4096 + row] = s;
        }
    }
}

// ---------------- Kernel D: fused stat-merge + normalize + attn write + AV + atomic acc.
// grid (16 ks, 4 iT, 4 b) = 256 blocks, block 256. Tile 256 i x 64 j, 8i x 8d/thread.
#define PSTR 260   // s_p row stride in h2v (1040 B, 16B-aligned; scatter ~4-way)
__global__ __launch_bounds__(256)
void kd_av(const _Float16* __restrict__ l16, const float* __restrict__ smax,
           const float* __restrict__ ssum, const float* __restrict__ x,
           float* __restrict__ attn, float* __restrict__ out) {
    __shared__ __align__(16) h2v s_p[32 * PSTR];  // [jp][i] : (a[i,2jp],a[i,2jp+1])
    __shared__ __align__(16) h2v s_x[32 * 64];    // [jp][d] : (x[2jp,d],x[2jp+1,d])
    __shared__ float s_m[256];
    __shared__ float s_il[256];
    const int t  = threadIdx.x;
    const int ks = blockIdx.x;     // j-chunk (64 wide)
    const int iT = blockIdx.y;
    const int b  = blockIdx.z;
    const int j0 = ks * 64;
    const int gr = b * 1024 + iT * 256;   // global row base
    // merge 16 chunk stats for row gr+t
    {
        float mv[16], sv[16];
#pragma unroll
        for (int c = 0; c < 16; ++c) {
            mv[c] = smax[c * 4096 + gr + t];
            sv[c] = ssum[c * 4096 + gr + t];
        }
        float M = mv[0];
#pragma unroll
        for (int c = 1; c < 16; ++c) M = fmaxf(M, mv[c]);
        float L = 0.f;
#pragma unroll
        for (int c = 0; c < 16; ++c) L += sv[c] * __expf(mv[c] - M);
        s_m[t]  = M;
        s_il[t] = 1.0f / L;
    }
    // stage x as j-pair-packed fp16: 512 tasks
#pragma unroll
    for (int it = 0; it < 2; ++it) {
        const int idx = it * 256 + t;
        const int jp  = idx >> 4;
        const int d4  = (idx & 15) * 4;
        f4 r0 = ld4(&x[(size_t)(b * 1024 + j0 + jp * 2)     * 64 + d4]);
        f4 r1 = ld4(&x[(size_t)(b * 1024 + j0 + jp * 2 + 1) * 64 + d4]);
        F4H u;
        u.h[0] = pack2(r0.x, r1.x); u.h[1] = pack2(r0.y, r1.y);
        u.h[2] = pack2(r0.z, r1.z); u.h[3] = pack2(r0.w, r1.w);
        st4((float*)&s_x[jp * 64 + d4], u.f);
    }
    __syncthreads();
    // stage logits: normalize, write attn fp32, scatter fp16 pairs to s_p
#pragma unroll 2
    for (int it = 0; it < 8; ++it) {
        const int idx = it * 256 + t;
        const int rl  = idx >> 3;          // 0..255
        const int j8  = (idx & 7) * 8;
        F4H u;
        u.f = ld4((const float*)&l16[(size_t)(gr + rl) * 1024 + j0 + j8]);
        const float m  = s_m[rl];
        const float il = s_il[rl];
        float p[8];
#pragma unroll
        for (int k = 0; k < 4; ++k) {
            p[2 * k]     = __expf((float)u.h[k].x - m) * il;
            p[2 * k + 1] = __expf((float)u.h[k].y - m) * il;
        }
        float* ap = &attn[(size_t)(gr + rl) * 1024 + j0 + j8];
        st4(ap,     make_float4(p[0], p[1], p[2], p[3]));
        st4(ap + 4, make_float4(p[4], p[5], p[6], p[7]));
        const int jp0 = (idx & 7) * 4;
#pragma unroll
        for (int k = 0; k < 4; ++k)
            s_p[(jp0 + k) * PSTR + rl] = pack2(p[2 * k], p[2 * k + 1]);
    }
    __syncthreads();
    const int tx = t & 7;   // d oct
    const int ty = t >> 3;  // i oct (0..31)
    float acc[8][8];
#pragma unroll
    for (int ii = 0; ii < 8; ++ii)
#pragma unroll
        for (int dd = 0; dd < 8; ++dd) acc[ii][dd] = 0.f;
#pragma unroll 4
    for (int jp = 0; jp < 32; ++jp) {
        F4H a0, a1, x0, x1;
        a0.f = ld4((const float*)&s_p[jp * PSTR + ty * 8]);      // 8-lane broadcast
        a1.f = ld4((const float*)&s_p[jp * PSTR + ty * 8 + 4]);
        x0.f = ld4((const float*)&s_x[jp * 64 + tx * 8]);        // 8-lane broadcast
        x1.f = ld4((const float*)&s_x[jp * 64 + tx * 8 + 4]);
        h2v aa[8] = {a0.h[0], a0.h[1], a0.h[2], a0.h[3], a1.h[0], a1.h[1], a1.h[2], a1.h[3]};
        h2v xx[8] = {x0.h[0], x0.h[1], x0.h[2], x0.h[3], x1.h[0], x1.h[1], x1.h[2], x1.h[3]};
#pragma unroll
        for (int ii = 0; ii < 8; ++ii)
#pragma unroll
            for (int dd = 0; dd < 8; ++dd)
                acc[ii][dd] = fdot2f(aa[ii], xx[dd], acc[ii][dd]);
    }
#pragma unroll
    for (int ii = 0; ii < 8; ++ii)
#pragma unroll
        for (int dd = 0; dd < 8; ++dd)
            atomicAdd(&out[(size_t)(gr + ty * 8 + ii) * 64 + tx * 8 + dd], acc[ii][dd]);
}

extern "C" void kernel_launch(void* const* d_in, const int* in_sizes, int n_in,
                              void* d_out, int out_size, void* d_ws, size_t ws_size,
                              hipStream_t stream) {
    const float* x  = (const float*)d_in[0];
    const float* W1 = (const float*)d_in[1];
    const float* b1 = (const float*)d_in[2];
    const float* W2 = (const float*)d_in[3];
    // d_in[4] = b2: softmax shift-invariance -> unused.
    float* out = (float*)d_out;
    float* ws  = (float*)d_ws;
    h2v*      hiP  = (h2v*)(ws + WS_HIP);
    h2v*      hjP  = (h2v*)(ws + WS_HJP);
    _Float16* l16  = (_Float16*)(ws + WS_L16);
    float*    smax = ws + WS_SMAX;
    float*    ssum = ws + WS_SSUM;

    ka_proj  <<<dim3(16, 4, 2), 256, 0, stream>>>(x, W1, b1, hiP, hjP, out);
    kb_logits<<<dim3(16, 8, 4), 256, 0, stream>>>(hiP, hjP, W2, l16, smax, ssum);
    kd_av    <<<dim3(16, 4, 4), 256, 0, stream>>>(l16, smax, ssum, x,
                                                  out + ATTN_OFF, out);
}

// Round 4
// 103.919 us; speedup vs baseline: 2.0707x; 2.0707x over previous
//
#include <hip/hip_runtime.h>

// Problem: B=4, N=1024, H=64.
// d_out: [0..262143] updated (b,i,d) fp32 ; [262144..4456447] attn (b,i,j) fp32
#define ATTN_OFF 262144

// ws float-slot offsets (1 slot = 4B):
#define WS_HIP  0          // hiP h2v-packed [b][32 hp][1024 i]        131072 slots
#define WS_HJP  131072     // hjP same                                  131072
#define WS_L16  262144     // logits fp16 [b][1024][1024]              2097152
#define WS_SMAX 2359296    // smax [16 chunk][4096 row] fp32             65536
#define WS_SSUM 2424832    // ssum [16][4096] fp32                       65536
#define WS_PART 2490368    // part [16][4096][64] fp32                 4194304

typedef float4 f4;
typedef _Float16 h2v __attribute__((ext_vector_type(2)));

union F4H { f4 f; h2v h[4]; };
union F2H { float2 f; h2v h[2]; };

__device__ __forceinline__ f4 ld4(const float* p) { return *reinterpret_cast<const f4*>(p); }
__device__ __forceinline__ void st4(float* p, f4 v) { *reinterpret_cast<f4*>(p) = v; }
__device__ __forceinline__ float fdot2f(h2v a, h2v b, float c) {
    return __builtin_amdgcn_fdot2(a, b, c, false);   // v_dot2_f32_f16
}
__device__ __forceinline__ h2v pack2(float a, float b) {
    h2v r; r.x = (_Float16)a; r.y = (_Float16)b; return r;
}

// ---------------- Kernel A: hi' = x@W1a^T + b1 ; hj = x@W1b^T. fp16 h-pair packed out.
__global__ __launch_bounds__(256, 4)
void ka_proj(const float* __restrict__ x, const float* __restrict__ W1,
             const float* __restrict__ b1,
             h2v* __restrict__ hiP, h2v* __restrict__ hjP) {
    __shared__ float xT[64 * 68];   // xT[d][i]
    __shared__ float w1T[64 * 68];  // w1T[d][c] = W1[c][z*64+d]
    const int t  = threadIdx.x;
    const int i0 = blockIdx.x * 64;
    const int b  = blockIdx.y;
    const int z  = blockIdx.z;
    const int lo = t & 15;
    const int dq = t >> 4;
#pragma unroll
    for (int p = 0; p < 4; ++p) {
        const int il = p * 16 + lo;
        f4 v = ld4(&x[(size_t)(b * 1024 + i0 + il) * 64 + dq * 4]);
        xT[(dq * 4 + 0) * 68 + il] = v.x;
        xT[(dq * 4 + 1) * 68 + il] = v.y;
        xT[(dq * 4 + 2) * 68 + il] = v.z;
        xT[(dq * 4 + 3) * 68 + il] = v.w;
        f4 w = ld4(&W1[(size_t)il * 128 + z * 64 + dq * 4]);
        w1T[(dq * 4 + 0) * 68 + il] = w.x;
        w1T[(dq * 4 + 1) * 68 + il] = w.y;
        w1T[(dq * 4 + 2) * 68 + il] = w.z;
        w1T[(dq * 4 + 3) * 68 + il] = w.w;
    }
    __syncthreads();
    const int tx = t & 15;   // channel quad
    const int ty = t >> 4;   // i quad
    float acc[4][4];
    if (z == 0) {
        f4 bv = ld4(&b1[tx * 4]);
        float ba[4] = {bv.x, bv.y, bv.z, bv.w};
#pragma unroll
        for (int ii = 0; ii < 4; ++ii)
#pragma unroll
            for (int cc = 0; cc < 4; ++cc) acc[ii][cc] = ba[cc];
    } else {
#pragma unroll
        for (int ii = 0; ii < 4; ++ii)
#pragma unroll
            for (int cc = 0; cc < 4; ++cc) acc[ii][cc] = 0.f;
    }
#pragma unroll 8
    for (int d = 0; d < 64; ++d) {
        f4 xv = ld4(&xT[d * 68 + ty * 4]);
        f4 wv = ld4(&w1T[d * 68 + tx * 4]);
        float xa[4] = {xv.x, xv.y, xv.z, xv.w};
        float wa[4] = {wv.x, wv.y, wv.z, wv.w};
#pragma unroll
        for (int ii = 0; ii < 4; ++ii)
#pragma unroll
            for (int cc = 0; cc < 4; ++cc)
                acc[ii][cc] = fmaf(xa[ii], wa[cc], acc[ii][cc]);
    }
    h2v* outp = z ? hjP : hiP;
#pragma unroll
    for (int p = 0; p < 2; ++p) {
        F4H u;
#pragma unroll
        for (int ii = 0; ii < 4; ++ii)
            u.h[ii] = pack2(acc[ii][p * 2 + 0], acc[ii][p * 2 + 1]);
        st4((float*)&outp[(size_t)(b * 32 + tx * 2 + p) * 1024 + i0 + ty * 4], u.f);
    }
}

// ---------------- Kernel B: logits (fp16) + per-chunk softmax stats. dot2 inner loop.
__global__ __launch_bounds__(256, 4)
void kb_logits(const h2v* __restrict__ hiP, const h2v* __restrict__ hjP,
               const float* __restrict__ W2, _Float16* __restrict__ l16,
               float* __restrict__ smax, float* __restrict__ ssum) {
    __shared__ __align__(16) h2v s_hi[32 * 128];  // [hp][i]
    __shared__ __align__(16) h2v s_hj[32 * 64];   // [hp][j]
    __shared__ h2v s_w2[32];
    const int t  = threadIdx.x;
    const int jT = blockIdx.x;
    const int iT = blockIdx.y;
    const int b  = blockIdx.z;
#pragma unroll
    for (int p = 0; p < 4; ++p) {
        const int idx = p * 256 + t;
        const int hp  = idx >> 5;
        const int c4  = (idx & 31) * 4;
        st4((float*)&s_hi[hp * 128 + c4],
            ld4((const float*)&hiP[(size_t)(b * 32 + hp) * 1024 + iT * 128 + c4]));
    }
#pragma unroll
    for (int p = 0; p < 2; ++p) {
        const int idx = p * 256 + t;
        const int hp  = idx >> 4;
        const int c4  = (idx & 15) * 4;
        st4((float*)&s_hj[hp * 64 + c4],
            ld4((const float*)&hjP[(size_t)(b * 32 + hp) * 1024 + jT * 64 + c4]));
    }
    if (t < 16) {
        f4 w = ld4(&W2[t * 4]);
        s_w2[t * 2]     = pack2(w.x, w.y);
        s_w2[t * 2 + 1] = pack2(w.z, w.w);
    }
    __syncthreads();
    const int tx = t & 15;  // j quad
    const int ty = t >> 4;  // i oct
    float acc[8][4];
#pragma unroll
    for (int ii = 0; ii < 8; ++ii)
#pragma unroll
        for (int jj = 0; jj < 4; ++jj) acc[ii][jj] = 0.f;
    const h2v z2 = (h2v)0;
#pragma unroll 4
    for (int hp = 0; hp < 32; ++hp) {
        F4H a0, a1, bb;
        a0.f = ld4((const float*)&s_hi[hp * 128 + ty * 8]);
        a1.f = ld4((const float*)&s_hi[hp * 128 + ty * 8 + 4]);
        bb.f = ld4((const float*)&s_hj[hp * 64 + tx * 4]);
        const h2v w2p = s_w2[hp];
#pragma unroll
        for (int ii = 0; ii < 8; ++ii) {
            const h2v av = (ii < 4) ? a0.h[ii] : a1.h[ii - 4];
#pragma unroll
            for (int jj = 0; jj < 4; ++jj) {
                h2v r = __builtin_elementwise_max(av + bb.h[jj], z2);
                acc[ii][jj] = fdot2f(r, w2p, acc[ii][jj]);
            }
        }
    }
#pragma unroll
    for (int ii = 0; ii < 8; ++ii) {
        const int row = b * 1024 + iT * 128 + ty * 8 + ii;
        F2H uo;
        uo.h[0] = pack2(acc[ii][0], acc[ii][1]);
        uo.h[1] = pack2(acc[ii][2], acc[ii][3]);
        *reinterpret_cast<float2*>(&l16[(size_t)row * 1024 + jT * 64 + tx * 4]) = uo.f;
        float m = fmaxf(fmaxf(acc[ii][0], acc[ii][1]), fmaxf(acc[ii][2], acc[ii][3]));
#pragma unroll
        for (int d = 1; d < 16; d <<= 1) m = fmaxf(m, __shfl_xor(m, d));
        float s = __expf(acc[ii][0] - m) + __expf(acc[ii][1] - m) +
                  __expf(acc[ii][2] - m) + __expf(acc[ii][3] - m);
#pragma unroll
        for (int d = 1; d < 16; d <<= 1) s += __shfl_xor(s, d);
        if (tx == 0) {
            smax[jT * 4096 + row] = m;
            ssum[jT * 4096 + row] = s;
        }
    }
}

// ---------------- Kernel D: stats-merge + normalize + attn write + AV partials (NO atomics).
// grid (16 ks, 8 iT, 4 b) = 512 blocks (2/CU), block 256. Tile 128 i x 64 j, 8i x 4d/thread.
#define PS 132   // s_p row stride in h2v (528 B)
__global__ __launch_bounds__(256, 2)
void kd_av(const _Float16* __restrict__ l16, const float* __restrict__ smax,
           const float* __restrict__ ssum, const float* __restrict__ x,
           float* __restrict__ attn, float* __restrict__ part) {
    __shared__ __align__(16) h2v s_p[32 * PS];    // [jp][i] : (a[i,2jp],a[i,2jp+1])
    __shared__ __align__(16) h2v s_x[32 * 64];    // [jp][d] : (x[2jp,d],x[2jp+1,d])
    __shared__ float s_m[128];
    __shared__ float s_il[128];
    const int t  = threadIdx.x;
    const int ks = blockIdx.x;            // j-chunk (64 wide)
    const int iT = blockIdx.y;            // 0..7 (128 rows)
    const int b  = blockIdx.z;
    const int j0 = ks * 64;
    const int gr = b * 1024 + iT * 128;   // global row base
    if (t < 128) {                        // merge 16 chunk stats for row gr+t
        float mv[16], sv[16];
#pragma unroll
        for (int c = 0; c < 16; ++c) {
            mv[c] = smax[c * 4096 + gr + t];
            sv[c] = ssum[c * 4096 + gr + t];
        }
        float M = mv[0];
#pragma unroll
        for (int c = 1; c < 16; ++c) M = fmaxf(M, mv[c]);
        float L = 0.f;
#pragma unroll
        for (int c = 0; c < 16; ++c) L += sv[c] * __expf(mv[c] - M);
        s_m[t]  = M;
        s_il[t] = 1.0f / L;
    }
    // stage x as j-pair-packed fp16
#pragma unroll
    for (int it = 0; it < 2; ++it) {
        const int idx = it * 256 + t;
        const int jp  = idx >> 4;
        const int d4  = (idx & 15) * 4;
        f4 r0 = ld4(&x[(size_t)(b * 1024 + j0 + jp * 2)     * 64 + d4]);
        f4 r1 = ld4(&x[(size_t)(b * 1024 + j0 + jp * 2 + 1) * 64 + d4]);
        F4H u;
        u.h[0] = pack2(r0.x, r1.x); u.h[1] = pack2(r0.y, r1.y);
        u.h[2] = pack2(r0.z, r1.z); u.h[3] = pack2(r0.w, r1.w);
        st4((float*)&s_x[jp * 64 + d4], u.f);
    }
    __syncthreads();
    // stage logits: exp-normalize, write attn fp32, scatter fp16 pairs to s_p
#pragma unroll 2
    for (int it = 0; it < 4; ++it) {
        const int idx = it * 256 + t;
        const int rl  = idx >> 3;          // 0..127
        const int j8  = (idx & 7) * 8;
        F4H u;
        u.f = ld4((const float*)&l16[(size_t)(gr + rl) * 1024 + j0 + j8]);
        const float m  = s_m[rl];
        const float il = s_il[rl];
        float p[8];
#pragma unroll
        for (int k = 0; k < 4; ++k) {
            p[2 * k]     = __expf((float)u.h[k].x - m) * il;
            p[2 * k + 1] = __expf((float)u.h[k].y - m) * il;
        }
        float* ap = &attn[(size_t)(gr + rl) * 1024 + j0 + j8];
        st4(ap,     make_float4(p[0], p[1], p[2], p[3]));
        st4(ap + 4, make_float4(p[4], p[5], p[6], p[7]));
        const int jp0 = (idx & 7) * 4;
#pragma unroll
        for (int k = 0; k < 4; ++k)
            s_p[(jp0 + k) * PS + rl] = pack2(p[2 * k], p[2 * k + 1]);
    }
    __syncthreads();
    const int tx = t & 15;  // d quad
    const int ty = t >> 4;  // i oct (0..15)
    float acc[8][4];
#pragma unroll
    for (int ii = 0; ii < 8; ++ii)
#pragma unroll
        for (int dd = 0; dd < 4; ++dd) acc[ii][dd] = 0.f;
#pragma unroll 4
    for (int jp = 0; jp < 32; ++jp) {
        F4H a0, a1, xv;
        a0.f = ld4((const float*)&s_p[jp * PS + ty * 8]);
        a1.f = ld4((const float*)&s_p[jp * PS + ty * 8 + 4]);
        xv.f = ld4((const float*)&s_x[jp * 64 + tx * 4]);
        h2v aa[8] = {a0.h[0], a0.h[1], a0.h[2], a0.h[3],
                     a1.h[0], a1.h[1], a1.h[2], a1.h[3]};
#pragma unroll
        for (int ii = 0; ii < 8; ++ii)
#pragma unroll
            for (int dd = 0; dd < 4; ++dd)
                acc[ii][dd] = fdot2f(aa[ii], xv.h[dd], acc[ii][dd]);
    }
#pragma unroll
    for (int ii = 0; ii < 8; ++ii) {
        f4 o = make_float4(acc[ii][0], acc[ii][1], acc[ii][2], acc[ii][3]);
        st4(&part[(size_t)(ks * 4096 + gr + ty * 8 + ii) * 64 + tx * 4], o);
    }
}

// ---------------- Kernel E: updated = sum of 16 partials -> d_out[0:262144]
__global__ __launch_bounds__(256)
void ke_reduce(const float* __restrict__ part, float* __restrict__ out) {
    const int g = blockIdx.x * 256 + threadIdx.x;  // f4 index, 65536 total
    f4 a = ld4(&part[(size_t)g * 4]);
#pragma unroll
    for (int ks = 1; ks < 16; ++ks) {
        f4 v = ld4(&part[(size_t)ks * 262144 + g * 4]);
        a.x += v.x; a.y += v.y; a.z += v.z; a.w += v.w;
    }
    st4(&out[(size_t)g * 4], a);
}

extern "C" void kernel_launch(void* const* d_in, const int* in_sizes, int n_in,
                              void* d_out, int out_size, void* d_ws, size_t ws_size,
                              hipStream_t stream) {
    const float* x  = (const float*)d_in[0];
    const float* W1 = (const float*)d_in[1];
    const float* b1 = (const float*)d_in[2];
    const float* W2 = (const float*)d_in[3];
    // d_in[4] = b2: softmax shift-invariance -> unused.
    float* out = (float*)d_out;
    float* ws  = (float*)d_ws;
    h2v*      hiP  = (h2v*)(ws + WS_HIP);
    h2v*      hjP  = (h2v*)(ws + WS_HJP);
    _Float16* l16  = (_Float16*)(ws + WS_L16);
    float*    smax = ws + WS_SMAX;
    float*    ssum = ws + WS_SSUM;
    float*    part = ws + WS_PART;

    ka_proj  <<<dim3(16, 4, 2), 256, 0, stream>>>(x, W1, b1, hiP, hjP);
    kb_logits<<<dim3(16, 8, 4), 256, 0, stream>>>(hiP, hjP, W2, l16, smax, ssum);
    kd_av    <<<dim3(16, 8, 4), 256, 0, stream>>>(l16, smax, ssum, x,
                                                  out + ATTN_OFF, part);
    ke_reduce<<<dim3(256),      256, 0, stream>>>(part, out);
}